// Round 4
// baseline (196.323 us; speedup 1.0000x reference)
//
#include <hip/hip_runtime.h>
#include <cstdint>
#include <cstddef>

#define BB 32
#define SS 1024
#define EE 512
#define UU 512
#define DD 512

typedef unsigned short ushort_t;
typedef __attribute__((ext_vector_type(8))) short s16x8;
typedef __attribute__((ext_vector_type(4))) float f32x4;

#define AS1(p) ((const __attribute__((address_space(1))) void*)(const void*)(p))
#define AS3(p) ((__attribute__((address_space(3))) void*)(void*)(p))

// round-to-nearest-even f32 -> bf16 bits; also returns the rounded value as f32
__device__ inline ushort_t bf16_rn(float x, float& hi_f) {
    uint32_t u = __float_as_uint(x);
    uint32_t r = (u + 0x7FFFu + ((u >> 16) & 1u)) >> 16;
    hi_f = __uint_as_float(r << 16);
    return (ushort_t)r;
}

__device__ inline float fast_tanh(float x) {
    float ax = fminf(fabsf(x), 20.0f);
    float e2 = __expf(ax * 2.0f);
    float t  = 1.0f - __fdividef(2.0f, e2 + 1.0f);
    return (x < 0.0f) ? -t : t;
}

// ---------------- K1: prep ----------------
// blocks 0..127  : pack Ua into swizzled bf16-hi staging image UaSwz.
//   Tile (nt,kt) = 128n x 64k. chunk c in tile: n=c>>3, kp=c&7, ko=kp^(n&7).
//   chunk data = bf16_hi(Ua[kt*64+ko*8+j][nt*128+n]), j=0..7  (16B per chunk).
//   global_load_lds writes chunks linearly -> LDS holds XOR-swizzled tile.
// blocks 128..383: dec_proj = hidden_dec @ Wa  (256 blocks: (b, 64-col slice))
__global__ void prep_kernel(const float* __restrict__ Ua,
                            const float* __restrict__ hid,
                            const float* __restrict__ Wa,
                            ushort_t* __restrict__ UaSwz,
                            float* __restrict__ decp) {
    __shared__ float sm[256];
    int blk = blockIdx.x, t = threadIdx.x;
    if (blk < 128) {
        int g    = blk * 256 + t;       // chunk id 0..32767
        int tile = g >> 10;             // 0..31 = nt*8+kt
        int c    = g & 1023;
        int nt = tile >> 3, kt = tile & 7;
        int n = c >> 3, kp = c & 7;
        int ko = kp ^ (n & 7);
        int u  = nt * 128 + n;
        int e0 = kt * 64 + ko * 8;
        s16x8 v;
#pragma unroll
        for (int j = 0; j < 8; ++j) {
            float hf;
            v[j] = (short)bf16_rn(Ua[(size_t)(e0 + j) * UU + u], hf);
        }
        *(s16x8*)(UaSwz + (size_t)g * 8) = v;
    } else {
        int q2 = blk - 128;             // 0..255
        int b = q2 >> 3, q = q2 & 7;
        int uo = t & 63, ch = t >> 6;
        const float* h = hid + (size_t)b * DD;
        float a = 0.f;
        int d0 = ch * 128;
#pragma unroll 4
        for (int d = d0; d < d0 + 128; ++d)
            a = fmaf(h[d], Wa[(size_t)d * UU + q * 64 + uo], a);
        sm[t] = a;
        __syncthreads();
        if (t < 64) {
            float s = sm[t] + sm[64 + t] + sm[128 + t] + sm[192 + t];
            decp[(size_t)b * UU + q * 64 + t] = s;
        }
    }
}

// ---------------- K2: fused scores kernel (u-split partials) ----------------
// scpart[uh][b][s] = sum_{u in uh-half} tanh( (enc[b,s,:]@Ua)[u] + decp[b,u] ) * Va[u]
// grid 1024: (b, 64-row s-tile, u-half). 4 waves x 16 rows. (a_hi+a_lo)*b_hi MFMA.
__global__ __launch_bounds__(256, 4)
void scores_kernel(const float* __restrict__ enc,
                   const ushort_t* __restrict__ UaSwz,
                   const float* __restrict__ decp,
                   const float* __restrict__ Va,
                   float* __restrict__ scpart) {
    __shared__ __align__(16) ushort_t lds_b[2][128 * 64];
    __shared__ float lds_dv[512];   // [0..255]=decp slice, [256..511]=Va slice

    const int tid  = threadIdx.x;
    const int lane = tid & 63;
    const int wave = tid >> 6;
    // bijective XCD-chunked swizzle: physical p, p+8 -> logical L, L+1 (uh pair
    // shares enc rows on the same XCD's L2)
    const int p  = blockIdx.x;
    const int L  = (p & 7) * 128 + (p >> 3);
    const int uh = L & 1;
    const int st = (L >> 1) & 15;
    const int b  = L >> 5;
    const int s0 = st * 64;

    // decp/Va slice for this u-half -> LDS
    lds_dv[tid]       = decp[(size_t)b * UU + uh * 256 + tid];
    lds_dv[256 + tid] = Va[uh * 256 + tid];

    // ---- A fragments: 16 rows/wave, full K=512 -> 16 k-steps, hi/lo regs ----
    // lane holds row (lane&15); k = ks*32 + (lane>>4)*8 + j
    const float* A = enc + ((size_t)b * SS + s0 + wave * 16 + (lane & 15)) * EE
                         + ((lane >> 4) * 8);
    s16x8 a_hi[16], a_lo[16];
#pragma unroll
    for (int ks = 0; ks < 16; ++ks) {
        f32x4 v0 = *(const f32x4*)(A + ks * 32);
        f32x4 v1 = *(const f32x4*)(A + ks * 32 + 4);
        s16x8 sh, sl;
#pragma unroll
        for (int j = 0; j < 4; ++j) {
            float hf, d;
            sh[j]     = (short)bf16_rn(v0[j], hf);
            sl[j]     = (short)bf16_rn(v0[j] - hf, d);
            sh[4 + j] = (short)bf16_rn(v1[j], hf);
            sl[4 + j] = (short)bf16_rn(v1[j] - hf, d);
        }
        a_hi[ks] = sh;
        a_lo[ks] = sl;
    }
    __syncthreads();   // dv visible; vmcnt==0 entering pipeline

    // per-lane swizzled read offsets (shorts)
    const int nl  = lane & 15;
    const int kq  = lane >> 4;
    const int l7  = lane & 7;
    const int rb  = nl * 64;
    const int kp0 = ((0 + kq) ^ l7) * 8;
    const int kp1 = ((4 + kq) ^ l7) * 8;

    // stage one 16KB tile (hi only): 4 x global_load_lds(16B) per wave
#define STAGE(tile, par)                                                        \
    {                                                                           \
        _Pragma("unroll")                                                       \
        for (int i = 0; i < 4; ++i) {                                           \
            __builtin_amdgcn_global_load_lds(                                   \
                AS1(UaSwz + (size_t)(tile) * 8192 +                             \
                    (((wave * 4 + i) * 64 + lane) * 8)),                        \
                AS3(&lds_b[par][(wave * 4 + i) * 512]), 16, 0, 0);              \
        }                                                                       \
    }

    float sp0 = 0.f, sp1 = 0.f, sp2 = 0.f, sp3 = 0.f;
    const int tbase = uh * 16;         // tiles [tbase, tbase+16)

    STAGE(tbase, 0);                   // prologue

#pragma unroll 1
    for (int pass = 0; pass < 2; ++pass) {
        f32x4 acc[8];
#pragma unroll
        for (int nf = 0; nf < 8; ++nf) acc[nf] = f32x4{0.f, 0.f, 0.f, 0.f};

#pragma unroll
        for (int kt = 0; kt < 8; ++kt) {
            int t8  = pass * 8 + kt;                  // 0..15 (buffer parity)
            int nxt = (t8 < 15) ? (t8 + 1) : 0;       // dummy re-stage at end
            STAGE(tbase + nxt, (t8 + 1) & 1);
            asm volatile("s_waitcnt vmcnt(4)" ::: "memory");
            __builtin_amdgcn_s_barrier();             // tile t8 ready

            const ushort_t* bp = lds_b[t8 & 1];
#pragma unroll
            for (int ks = 0; ks < 2; ++ks) {
                const int kpo = ks ? kp1 : kp0;
#pragma unroll
                for (int nf = 0; nf < 8; ++nf) {
                    s16x8 bh = *(const s16x8*)(bp + nf * 1024 + rb + kpo);
                    // K-position of this tile depends on kt ONLY (compile-time
                    // in the unrolled loop -> static a-frag index, no scratch)
                    acc[nf] = __builtin_amdgcn_mfma_f32_16x16x32_bf16(
                        a_hi[kt * 2 + ks], bh, acc[nf], 0, 0, 0);
                    acc[nf] = __builtin_amdgcn_mfma_f32_16x16x32_bf16(
                        a_lo[kt * 2 + ks], bh, acc[nf], 0, 0, 0);
                }
            }
            asm volatile("s_waitcnt lgkmcnt(0)" ::: "memory");
            __builtin_amdgcn_s_barrier();             // reads done before overwrite
        }

        // ---- epilogue: e = tanh(acc + decp), sp += e * Va ----
        // C/D layout: col = lane&15, row = (lane>>4)*4 + reg
#pragma unroll
        for (int nf = 0; nf < 8; ++nf) {
            int n = pass * 128 + nf * 16 + nl;        // col within this u-half
            float dp = lds_dv[n];
            float va = lds_dv[256 + n];
            sp0 += fast_tanh(acc[nf][0] + dp) * va;
            sp1 += fast_tanh(acc[nf][1] + dp) * va;
            sp2 += fast_tanh(acc[nf][2] + dp) * va;
            sp3 += fast_tanh(acc[nf][3] + dp) * va;
        }
    }
    asm volatile("s_waitcnt vmcnt(0)" ::: "memory");  // drain dummy stage

    // reduce across the 16 column-lanes of each row group
#pragma unroll
    for (int off = 1; off < 16; off <<= 1) {
        sp0 += __shfl_xor(sp0, off, 64);
        sp1 += __shfl_xor(sp1, off, 64);
        sp2 += __shfl_xor(sp2, off, 64);
        sp3 += __shfl_xor(sp3, off, 64);
    }
    if (nl == 0) {
        int m = kq * 4;
        float* o = scpart + (size_t)uh * BB * SS + (size_t)b * SS + s0 + wave * 16 + m;
        o[0] = sp0; o[1] = sp1; o[2] = sp2; o[3] = sp3;
    }
#undef STAGE
}

// ---------------- K3: fused softmax + context partials ----------------
// block (b, scn): sum the two u-half score partials, derive row max/sum,
// weight this block's 64-s chunk of enc. 512 blocks.
__global__ void context_partial(const float* __restrict__ enc,
                                const float* __restrict__ scp,  // [2][B][S]
                                float* __restrict__ part) {     // [16][B][E]
    __shared__ float red[8];
    __shared__ float al[64];
    int bid = blockIdx.x;
    int b = bid >> 4, scn = bid & 15;
    int t = threadIdx.x, lane = t & 63, wave = t >> 6;

    f32x4 v0 = *(const f32x4*)(scp + (size_t)b * SS + t * 4);
    f32x4 v1 = *(const f32x4*)(scp + (size_t)BB * SS + (size_t)b * SS + t * 4);
    f32x4 v = {v0[0] + v1[0], v0[1] + v1[1], v0[2] + v1[2], v0[3] + v1[3]};

    float m = fmaxf(fmaxf(v[0], v[1]), fmaxf(v[2], v[3]));
#pragma unroll
    for (int off = 1; off < 64; off <<= 1) m = fmaxf(m, __shfl_xor(m, off, 64));
    if (lane == 0) red[wave] = m;
    __syncthreads();
    m = fmaxf(fmaxf(red[0], red[1]), fmaxf(red[2], red[3]));

    float e0 = __expf(v[0] - m), e1 = __expf(v[1] - m);
    float e2 = __expf(v[2] - m), e3 = __expf(v[3] - m);
    float s = e0 + e1 + e2 + e3;
#pragma unroll
    for (int off = 1; off < 64; off <<= 1) s += __shfl_xor(s, off, 64);
    if (lane == 0) red[4 + wave] = s;
    __syncthreads();
    s = red[4] + red[5] + red[6] + red[7];
    float inv = 1.0f / s;

    // this block's 64-s chunk: rows scn*64 .. scn*64+63, held by threads
    // [scn*16, scn*16+16), 4 rows each
    if (t >= scn * 16 && t < scn * 16 + 16) {
        int i0 = (t - scn * 16) * 4;
        al[i0 + 0] = e0 * inv; al[i0 + 1] = e1 * inv;
        al[i0 + 2] = e2 * inv; al[i0 + 3] = e3 * inv;
    }
    __syncthreads();

    const float* basep = enc + ((size_t)b * SS + scn * 64) * EE;
    float a0 = 0.f, a1 = 0.f;
#pragma unroll 4
    for (int si = 0; si < 64; ++si) {
        float w = al[si];
        a0 = fmaf(w, basep[(size_t)si * EE + t], a0);
        a1 = fmaf(w, basep[(size_t)si * EE + t + 256], a1);
    }
    float* pp = part + ((size_t)scn * BB + b) * EE;
    pp[t] = a0;
    pp[t + 256] = a1;
}

// ---------------- K4: deterministic reduce of 16 partials ----------------
__global__ void context_reduce(const float* __restrict__ part,
                               float* __restrict__ out) {
    int g = blockIdx.x * 256 + threadIdx.x;  // 0..16383
    float s = 0.f;
#pragma unroll
    for (int scn = 0; scn < 16; ++scn) s += part[(size_t)scn * BB * EE + g];
    out[g] = s;
}

extern "C" void kernel_launch(void* const* d_in, const int* in_sizes, int n_in,
                              void* d_out, int out_size, void* d_ws, size_t ws_size,
                              hipStream_t stream) {
    const float* enc = (const float*)d_in[0];   // [B,S,E]
    const float* hid = (const float*)d_in[1];   // [B,D]
    const float* Wa  = (const float*)d_in[2];   // [D,U]
    const float* Ua  = (const float*)d_in[3];   // [E,U]
    const float* Va  = (const float*)d_in[4];   // [U]
    float* out = (float*)d_out;                 // [B,E]

    char* ws = (char*)d_ws;
    float*    decp   = (float*)(ws);                  //  64 KB
    float*    scpart = (float*)(ws + 65536);          // 256 KB  [2][B][S]
    float*    part   = (float*)(ws + 327680);         //   1 MB  [16][B][E]
    ushort_t* UaSwz  = (ushort_t*)(ws + 1376256);     // 512 KB

    prep_kernel<<<384, 256, 0, stream>>>(Ua, hid, Wa, UaSwz, decp);
    scores_kernel<<<1024, 256, 0, stream>>>(enc, UaSwz, decp, Va, scpart);
    context_partial<<<512, 256, 0, stream>>>(enc, scpart, part);
    context_reduce<<<64, 256, 0, stream>>>(part, out);
}

// Round 5
// 88.080 us; speedup vs baseline: 2.2289x; 2.2289x over previous
//
#include <hip/hip_runtime.h>
#include <cstdint>
#include <cstddef>

#define BB 32
#define SS 1024
#define EE 512
#define UU 512
#define DD 512

typedef unsigned short ushort_t;
typedef __attribute__((ext_vector_type(8))) short s16x8;
typedef __attribute__((ext_vector_type(4))) float f32x4;

#define AS1(p) ((const __attribute__((address_space(1))) void*)(const void*)(p))
#define AS3(p) ((__attribute__((address_space(3))) void*)(void*)(p))

// round-to-nearest-even f32 -> bf16 bits; also returns the rounded value as f32
__device__ inline ushort_t bf16_rn(float x, float& hi_f) {
    uint32_t u = __float_as_uint(x);
    uint32_t r = (u + 0x7FFFu + ((u >> 16) & 1u)) >> 16;
    hi_f = __uint_as_float(r << 16);
    return (ushort_t)r;
}

__device__ inline float fast_tanh(float x) {
    float ax = fminf(fabsf(x), 20.0f);
    float e2 = __expf(ax * 2.0f);
    float t  = 1.0f - __fdividef(2.0f, e2 + 1.0f);
    return (x < 0.0f) ? -t : t;
}

// ---------------- K1: prep ----------------
// blocks 0..127  : pack Ua into swizzled bf16-hi staging image UaSwz.
//   Tile (nt,kt) = 128n x 64k. chunk c in tile: n=c>>3, kp=c&7, ko=kp^(n&7).
//   chunk data = bf16_hi(Ua[kt*64+ko*8+j][nt*128+n]), j=0..7  (16B per chunk).
//   global_load_lds writes chunks linearly -> LDS holds XOR-swizzled tile.
// blocks 128..383: dec_proj = hidden_dec @ Wa  (256 blocks: (b, 64-col slice))
__global__ void prep_kernel(const float* __restrict__ Ua,
                            const float* __restrict__ hid,
                            const float* __restrict__ Wa,
                            ushort_t* __restrict__ UaSwz,
                            float* __restrict__ decp) {
    __shared__ float sm[256];
    int blk = blockIdx.x, t = threadIdx.x;
    if (blk < 128) {
        int g    = blk * 256 + t;       // chunk id 0..32767
        int tile = g >> 10;             // 0..31 = nt*8+kt
        int c    = g & 1023;
        int nt = tile >> 3, kt = tile & 7;
        int n = c >> 3, kp = c & 7;
        int ko = kp ^ (n & 7);
        int u  = nt * 128 + n;
        int e0 = kt * 64 + ko * 8;
        s16x8 v;
#pragma unroll
        for (int j = 0; j < 8; ++j) {
            float hf;
            v[j] = (short)bf16_rn(Ua[(size_t)(e0 + j) * UU + u], hf);
        }
        *(s16x8*)(UaSwz + (size_t)g * 8) = v;
    } else {
        int q2 = blk - 128;             // 0..255
        int b = q2 >> 3, q = q2 & 7;
        int uo = t & 63, ch = t >> 6;
        const float* h = hid + (size_t)b * DD;
        float a = 0.f;
        int d0 = ch * 128;
#pragma unroll 4
        for (int d = d0; d < d0 + 128; ++d)
            a = fmaf(h[d], Wa[(size_t)d * UU + q * 64 + uo], a);
        sm[t] = a;
        __syncthreads();
        if (t < 64) {
            float s = sm[t] + sm[64 + t] + sm[128 + t] + sm[192 + t];
            decp[(size_t)b * UU + q * 64 + t] = s;
        }
    }
}

// ---------------- K2: fused scores kernel (u-split partials) ----------------
// scpart[uh][b][s] = sum_{u in uh-half} tanh( (enc[b,s,:]@Ua)[u] + decp[b,u] ) * Va[u]
// grid 1024: (b, 64-row s-tile, u-half). 4 waves x 16 rows. (a_hi+a_lo)*b_hi MFMA.
// launch_bounds(256,2): kernel holds ~160 live regs (A-frags 128 VGPR + acc 32
// AGPR) -- declaring 4 waves/EU caps the allocator and spills all A-frags to
// scratch (r4: 265MB scratch writes, 3x slower). HW still co-schedules 3/CU.
__global__ __launch_bounds__(256, 2)
void scores_kernel(const float* __restrict__ enc,
                   const ushort_t* __restrict__ UaSwz,
                   const float* __restrict__ decp,
                   const float* __restrict__ Va,
                   float* __restrict__ scpart) {
    __shared__ __align__(16) ushort_t lds_b[2][128 * 64];
    __shared__ float lds_dv[512];   // [0..255]=decp slice, [256..511]=Va slice

    const int tid  = threadIdx.x;
    const int lane = tid & 63;
    const int wave = tid >> 6;
    // bijective XCD-chunked swizzle: physical p, p+8 -> logical L, L+1 (uh pair
    // shares enc rows on the same XCD's L2)
    const int p  = blockIdx.x;
    const int L  = (p & 7) * 128 + (p >> 3);
    const int uh = L & 1;
    const int st = (L >> 1) & 15;
    const int b  = L >> 5;
    const int s0 = st * 64;

    // decp/Va slice for this u-half -> LDS
    lds_dv[tid]       = decp[(size_t)b * UU + uh * 256 + tid];
    lds_dv[256 + tid] = Va[uh * 256 + tid];

    // ---- A fragments: 16 rows/wave, full K=512 -> 16 k-steps, hi/lo regs ----
    // lane holds row (lane&15); k = ks*32 + (lane>>4)*8 + j
    const float* A = enc + ((size_t)b * SS + s0 + wave * 16 + (lane & 15)) * EE
                         + ((lane >> 4) * 8);
    s16x8 a_hi[16], a_lo[16];
#pragma unroll
    for (int ks = 0; ks < 16; ++ks) {
        f32x4 v0 = *(const f32x4*)(A + ks * 32);
        f32x4 v1 = *(const f32x4*)(A + ks * 32 + 4);
        s16x8 sh, sl;
#pragma unroll
        for (int j = 0; j < 4; ++j) {
            float hf, d;
            sh[j]     = (short)bf16_rn(v0[j], hf);
            sl[j]     = (short)bf16_rn(v0[j] - hf, d);
            sh[4 + j] = (short)bf16_rn(v1[j], hf);
            sl[4 + j] = (short)bf16_rn(v1[j] - hf, d);
        }
        a_hi[ks] = sh;
        a_lo[ks] = sl;
    }
    __syncthreads();   // dv visible; vmcnt==0 entering pipeline

    // per-lane swizzled read offsets (shorts)
    const int nl  = lane & 15;
    const int kq  = lane >> 4;
    const int l7  = lane & 7;
    const int rb  = nl * 64;
    const int kp0 = ((0 + kq) ^ l7) * 8;
    const int kp1 = ((4 + kq) ^ l7) * 8;

    // stage one 16KB tile (hi only): 4 x global_load_lds(16B) per wave
#define STAGE(tile, par)                                                        \
    {                                                                           \
        _Pragma("unroll")                                                       \
        for (int i = 0; i < 4; ++i) {                                           \
            __builtin_amdgcn_global_load_lds(                                   \
                AS1(UaSwz + (size_t)(tile) * 8192 +                             \
                    (((wave * 4 + i) * 64 + lane) * 8)),                        \
                AS3(&lds_b[par][(wave * 4 + i) * 512]), 16, 0, 0);              \
        }                                                                       \
    }

    float sp0 = 0.f, sp1 = 0.f, sp2 = 0.f, sp3 = 0.f;
    const int tbase = uh * 16;         // tiles [tbase, tbase+16)

    STAGE(tbase, 0);                   // prologue

#pragma unroll 1
    for (int pass = 0; pass < 2; ++pass) {
        f32x4 acc[8];
#pragma unroll
        for (int nf = 0; nf < 8; ++nf) acc[nf] = f32x4{0.f, 0.f, 0.f, 0.f};

#pragma unroll
        for (int kt = 0; kt < 8; ++kt) {
            int t8  = pass * 8 + kt;                  // 0..15 (buffer parity)
            int nxt = (t8 < 15) ? (t8 + 1) : 0;       // dummy re-stage at end
            STAGE(tbase + nxt, (t8 + 1) & 1);
            asm volatile("s_waitcnt vmcnt(4)" ::: "memory");
            __builtin_amdgcn_s_barrier();             // tile t8 ready

            const ushort_t* bp = lds_b[t8 & 1];
#pragma unroll
            for (int ks = 0; ks < 2; ++ks) {
                const int kpo = ks ? kp1 : kp0;
#pragma unroll
                for (int nf = 0; nf < 8; ++nf) {
                    s16x8 bh = *(const s16x8*)(bp + nf * 1024 + rb + kpo);
                    // K-position depends on kt ONLY (compile-time in the
                    // unrolled loop -> static a-frag index, no scratch)
                    acc[nf] = __builtin_amdgcn_mfma_f32_16x16x32_bf16(
                        a_hi[kt * 2 + ks], bh, acc[nf], 0, 0, 0);
                    acc[nf] = __builtin_amdgcn_mfma_f32_16x16x32_bf16(
                        a_lo[kt * 2 + ks], bh, acc[nf], 0, 0, 0);
                }
            }
            asm volatile("s_waitcnt lgkmcnt(0)" ::: "memory");
            __builtin_amdgcn_s_barrier();             // reads done before overwrite
        }

        // ---- epilogue: e = tanh(acc + decp), sp += e * Va ----
        // C/D layout: col = lane&15, row = (lane>>4)*4 + reg
#pragma unroll
        for (int nf = 0; nf < 8; ++nf) {
            int n = pass * 128 + nf * 16 + nl;        // col within this u-half
            float dp = lds_dv[n];
            float va = lds_dv[256 + n];
            sp0 += fast_tanh(acc[nf][0] + dp) * va;
            sp1 += fast_tanh(acc[nf][1] + dp) * va;
            sp2 += fast_tanh(acc[nf][2] + dp) * va;
            sp3 += fast_tanh(acc[nf][3] + dp) * va;
        }
    }
    asm volatile("s_waitcnt vmcnt(0)" ::: "memory");  // drain dummy stage

    // reduce across the 16 column-lanes of each row group
#pragma unroll
    for (int off = 1; off < 16; off <<= 1) {
        sp0 += __shfl_xor(sp0, off, 64);
        sp1 += __shfl_xor(sp1, off, 64);
        sp2 += __shfl_xor(sp2, off, 64);
        sp3 += __shfl_xor(sp3, off, 64);
    }
    if (nl == 0) {
        int m = kq * 4;
        float* o = scpart + (size_t)uh * BB * SS + (size_t)b * SS + s0 + wave * 16 + m;
        o[0] = sp0; o[1] = sp1; o[2] = sp2; o[3] = sp3;
    }
#undef STAGE
}

// ---------------- K3: fused softmax + context partials ----------------
// block (b, scn): sum the two u-half score partials, derive row max/sum,
// weight this block's 64-s chunk of enc. 512 blocks.
__global__ void context_partial(const float* __restrict__ enc,
                                const float* __restrict__ scp,  // [2][B][S]
                                float* __restrict__ part) {     // [16][B][E]
    __shared__ float red[8];
    __shared__ float al[64];
    int bid = blockIdx.x;
    int b = bid >> 4, scn = bid & 15;
    int t = threadIdx.x, lane = t & 63, wave = t >> 6;

    f32x4 v0 = *(const f32x4*)(scp + (size_t)b * SS + t * 4);
    f32x4 v1 = *(const f32x4*)(scp + (size_t)BB * SS + (size_t)b * SS + t * 4);
    f32x4 v = {v0[0] + v1[0], v0[1] + v1[1], v0[2] + v1[2], v0[3] + v1[3]};

    float m = fmaxf(fmaxf(v[0], v[1]), fmaxf(v[2], v[3]));
#pragma unroll
    for (int off = 1; off < 64; off <<= 1) m = fmaxf(m, __shfl_xor(m, off, 64));
    if (lane == 0) red[wave] = m;
    __syncthreads();
    m = fmaxf(fmaxf(red[0], red[1]), fmaxf(red[2], red[3]));

    float e0 = __expf(v[0] - m), e1 = __expf(v[1] - m);
    float e2 = __expf(v[2] - m), e3 = __expf(v[3] - m);
    float s = e0 + e1 + e2 + e3;
#pragma unroll
    for (int off = 1; off < 64; off <<= 1) s += __shfl_xor(s, off, 64);
    if (lane == 0) red[4 + wave] = s;
    __syncthreads();
    s = red[4] + red[5] + red[6] + red[7];
    float inv = 1.0f / s;

    // this block's 64-s chunk: rows scn*64 .. scn*64+63, held by threads
    // [scn*16, scn*16+16), 4 rows each
    if (t >= scn * 16 && t < scn * 16 + 16) {
        int i0 = (t - scn * 16) * 4;
        al[i0 + 0] = e0 * inv; al[i0 + 1] = e1 * inv;
        al[i0 + 2] = e2 * inv; al[i0 + 3] = e3 * inv;
    }
    __syncthreads();

    const float* basep = enc + ((size_t)b * SS + scn * 64) * EE;
    float a0 = 0.f, a1 = 0.f;
#pragma unroll 4
    for (int si = 0; si < 64; ++si) {
        float w = al[si];
        a0 = fmaf(w, basep[(size_t)si * EE + t], a0);
        a1 = fmaf(w, basep[(size_t)si * EE + t + 256], a1);
    }
    float* pp = part + ((size_t)scn * BB + b) * EE;
    pp[t] = a0;
    pp[t + 256] = a1;
}

// ---------------- K4: deterministic reduce of 16 partials ----------------
__global__ void context_reduce(const float* __restrict__ part,
                               float* __restrict__ out) {
    int g = blockIdx.x * 256 + threadIdx.x;  // 0..16383
    float s = 0.f;
#pragma unroll
    for (int scn = 0; scn < 16; ++scn) s += part[(size_t)scn * BB * EE + g];
    out[g] = s;
}

extern "C" void kernel_launch(void* const* d_in, const int* in_sizes, int n_in,
                              void* d_out, int out_size, void* d_ws, size_t ws_size,
                              hipStream_t stream) {
    const float* enc = (const float*)d_in[0];   // [B,S,E]
    const float* hid = (const float*)d_in[1];   // [B,D]
    const float* Wa  = (const float*)d_in[2];   // [D,U]
    const float* Ua  = (const float*)d_in[3];   // [E,U]
    const float* Va  = (const float*)d_in[4];   // [U]
    float* out = (float*)d_out;                 // [B,E]

    char* ws = (char*)d_ws;
    float*    decp   = (float*)(ws);                  //  64 KB
    float*    scpart = (float*)(ws + 65536);          // 256 KB  [2][B][S]
    float*    part   = (float*)(ws + 327680);         //   1 MB  [16][B][E]
    ushort_t* UaSwz  = (ushort_t*)(ws + 1376256);     // 512 KB

    prep_kernel<<<384, 256, 0, stream>>>(Ua, hid, Wa, UaSwz, decp);
    scores_kernel<<<1024, 256, 0, stream>>>(enc, UaSwz, decp, Va, scpart);
    context_partial<<<512, 256, 0, stream>>>(enc, scpart, part);
    context_reduce<<<64, 256, 0, stream>>>(part, out);
}

// Round 6
// 68.161 us; speedup vs baseline: 2.8803x; 1.2922x over previous
//
#include <hip/hip_runtime.h>
#include <cstdint>
#include <cstddef>

#define BB 32
#define SS 1024
#define EE 512
#define UU 512
#define DD 512

typedef unsigned short ushort_t;
typedef __attribute__((ext_vector_type(8))) short s16x8;
typedef __attribute__((ext_vector_type(4))) float f32x4;

#define AS1(p) ((const __attribute__((address_space(1))) void*)(const void*)(p))
#define AS3(p) ((__attribute__((address_space(3))) void*)(void*)(p))

// round-to-nearest-even f32 -> bf16 bits (used in prep only; off critical path)
__device__ inline ushort_t bf16_rn(float x, float& hi_f) {
    uint32_t u = __float_as_uint(x);
    uint32_t r = (u + 0x7FFFu + ((u >> 16) & 1u)) >> 16;
    hi_f = __uint_as_float(r << 16);
    return (ushort_t)r;
}

__device__ inline float fast_tanh(float x) {
    float ax = fminf(fabsf(x), 20.0f);
    float e2 = __expf(ax * 2.0f);
    float t  = 1.0f - __fdividef(2.0f, e2 + 1.0f);
    return (x < 0.0f) ? -t : t;
}

// ---------------- K1: prep ----------------
// blocks 0..127  : pack Ua into swizzled bf16-hi staging image UaSwz.
//   Tile (nt,kt) = 128n x 64k. chunk c in tile: n=c>>3, kp=c&7, ko=kp^(n&7).
//   chunk data = bf16_hi(Ua[kt*64+ko*8+j][nt*128+n]), j=0..7  (16B per chunk).
//   global_load_lds writes chunks linearly -> LDS holds XOR-swizzled tile.
// blocks 128..383: dec_proj = hidden_dec @ Wa  (256 blocks: (b, 64-col slice))
__global__ void prep_kernel(const float* __restrict__ Ua,
                            const float* __restrict__ hid,
                            const float* __restrict__ Wa,
                            ushort_t* __restrict__ UaSwz,
                            float* __restrict__ decp) {
    __shared__ float sm[256];
    int blk = blockIdx.x, t = threadIdx.x;
    if (blk < 128) {
        int g    = blk * 256 + t;       // chunk id 0..32767
        int tile = g >> 10;             // 0..31 = nt*8+kt
        int c    = g & 1023;
        int nt = tile >> 3, kt = tile & 7;
        int n = c >> 3, kp = c & 7;
        int ko = kp ^ (n & 7);
        int u  = nt * 128 + n;
        int e0 = kt * 64 + ko * 8;
        s16x8 v;
#pragma unroll
        for (int j = 0; j < 8; ++j) {
            float hf;
            v[j] = (short)bf16_rn(Ua[(size_t)(e0 + j) * UU + u], hf);
        }
        *(s16x8*)(UaSwz + (size_t)g * 8) = v;
    } else {
        int q2 = blk - 128;             // 0..255
        int b = q2 >> 3, q = q2 & 7;
        int uo = t & 63, ch = t >> 6;
        const float* h = hid + (size_t)b * DD;
        float a = 0.f;
        int d0 = ch * 128;
#pragma unroll 4
        for (int d = d0; d < d0 + 128; ++d)
            a = fmaf(h[d], Wa[(size_t)d * UU + q * 64 + uo], a);
        sm[t] = a;
        __syncthreads();
        if (t < 64) {
            float s = sm[t] + sm[64 + t] + sm[128 + t] + sm[192 + t];
            decp[(size_t)b * UU + q * 64 + t] = s;
        }
    }
}

// ---------------- K2: fused scores kernel ----------------
// scores[b,s] = sum_u tanh( (enc[b,s,:]@Ua)[u] + decp[b,u] ) * Va[u]
// 512 blocks (b, 64-row s-tile), 4 waves x 16 rows, full U per block
// (one A-prologue per enc row -- the u-split of r5 doubled it, -25% perf).
// A split: hi = truncate-to-bf16 (1 shift), lo = rn-trunc(x - hi); residual
// 2^-16 relative -> error stays B-side dominated (~1e-3).
// launch_bounds(256,2): kernel needs ~160 live unified regs; (256,4) caps at
// 128 and spills everything to scratch (r4: 265MB scratch writes, 3x slower).
__global__ __launch_bounds__(256, 2)
void scores_kernel(const float* __restrict__ enc,
                   const ushort_t* __restrict__ UaSwz,
                   const float* __restrict__ decp,
                   const float* __restrict__ Va,
                   float* __restrict__ scores) {
    __shared__ __align__(16) ushort_t lds_b[2][128 * 64];
    __shared__ float lds_dv[1024];  // [0..511]=decp row, [512..1023]=Va

    const int tid  = threadIdx.x;
    const int lane = tid & 63;
    const int wave = tid >> 6;
    const int bid  = blockIdx.x;
    const int b    = bid >> 4;
    const int s0   = (bid & 15) * 64;

    lds_dv[tid]       = decp[(size_t)b * UU + tid];
    lds_dv[256 + tid] = decp[(size_t)b * UU + 256 + tid];
    lds_dv[512 + tid] = Va[tid];
    lds_dv[768 + tid] = Va[256 + tid];

    // ---- A fragments: 16 rows/wave, full K=512 -> 16 k-steps, hi/lo regs ----
    // lane holds row (lane&15); k = ks*32 + (lane>>4)*8 + j
    const float* A = enc + ((size_t)b * SS + s0 + wave * 16 + (lane & 15)) * EE
                         + ((lane >> 4) * 8);
    s16x8 a_hi[16], a_lo[16];
#pragma unroll
    for (int ks = 0; ks < 16; ++ks) {
        f32x4 v0 = *(const f32x4*)(A + ks * 32);
        f32x4 v1 = *(const f32x4*)(A + ks * 32 + 4);
        s16x8 sh, sl;
#pragma unroll
        for (int j = 0; j < 4; ++j) {
            uint32_t u0 = __float_as_uint(v0[j]);
            sh[j] = (short)(u0 >> 16);
            float l0 = v0[j] - __uint_as_float(u0 & 0xFFFF0000u);
            sl[j] = (short)(__float_as_uint(l0) >> 16);
            uint32_t u1 = __float_as_uint(v1[j]);
            sh[4 + j] = (short)(u1 >> 16);
            float l1 = v1[j] - __uint_as_float(u1 & 0xFFFF0000u);
            sl[4 + j] = (short)(__float_as_uint(l1) >> 16);
        }
        a_hi[ks] = sh;
        a_lo[ks] = sl;
    }
    __syncthreads();   // dv visible; vmcnt==0 entering pipeline

    // per-lane swizzled read offsets (shorts)
    const int nl  = lane & 15;
    const int kq  = lane >> 4;
    const int l7  = lane & 7;
    const int rb  = nl * 64;
    const int kp0 = ((0 + kq) ^ l7) * 8;
    const int kp1 = ((4 + kq) ^ l7) * 8;

    // stage one 16KB tile (hi only): 4 x global_load_lds(16B) per wave
#define STAGE(tile, par)                                                        \
    {                                                                           \
        _Pragma("unroll")                                                       \
        for (int i = 0; i < 4; ++i) {                                           \
            __builtin_amdgcn_global_load_lds(                                   \
                AS1(UaSwz + (size_t)(tile) * 8192 +                             \
                    (((wave * 4 + i) * 64 + lane) * 8)),                        \
                AS3(&lds_b[par][(wave * 4 + i) * 512]), 16, 0, 0);              \
        }                                                                       \
    }

    float sp0 = 0.f, sp1 = 0.f, sp2 = 0.f, sp3 = 0.f;

    STAGE(0, 0);                       // prologue

#pragma unroll 1
    for (int nt = 0; nt < 4; ++nt) {
        f32x4 acc[8];
#pragma unroll
        for (int nf = 0; nf < 8; ++nf) acc[nf] = f32x4{0.f, 0.f, 0.f, 0.f};

#pragma unroll
        for (int kt = 0; kt < 8; ++kt) {
            int t8  = nt * 8 + kt;                    // 0..31
            int nxt = (t8 < 31) ? (t8 + 1) : 0;       // dummy re-stage at end
            STAGE(nxt, (t8 + 1) & 1);
            asm volatile("s_waitcnt vmcnt(4)" ::: "memory");
            __builtin_amdgcn_s_barrier();             // tile t8 ready

            const ushort_t* bp = lds_b[t8 & 1];
#pragma unroll
            for (int ks = 0; ks < 2; ++ks) {
                const int kpo = ks ? kp1 : kp0;
#pragma unroll
                for (int nf = 0; nf < 8; ++nf) {
                    s16x8 bh = *(const s16x8*)(bp + nf * 1024 + rb + kpo);
                    // K-position depends on kt only (compile-time index)
                    acc[nf] = __builtin_amdgcn_mfma_f32_16x16x32_bf16(
                        a_hi[kt * 2 + ks], bh, acc[nf], 0, 0, 0);
                    acc[nf] = __builtin_amdgcn_mfma_f32_16x16x32_bf16(
                        a_lo[kt * 2 + ks], bh, acc[nf], 0, 0, 0);
                }
            }
            asm volatile("s_waitcnt lgkmcnt(0)" ::: "memory");
            __builtin_amdgcn_s_barrier();             // reads done before overwrite
        }

        // ---- epilogue: e = tanh(acc + decp), sp += e * Va ----
        // C/D layout: col = lane&15, row = (lane>>4)*4 + reg
#pragma unroll
        for (int nf = 0; nf < 8; ++nf) {
            int n = nt * 128 + nf * 16 + nl;
            float dp = lds_dv[n];
            float va = lds_dv[512 + n];
            sp0 += fast_tanh(acc[nf][0] + dp) * va;
            sp1 += fast_tanh(acc[nf][1] + dp) * va;
            sp2 += fast_tanh(acc[nf][2] + dp) * va;
            sp3 += fast_tanh(acc[nf][3] + dp) * va;
        }
    }
    asm volatile("s_waitcnt vmcnt(0)" ::: "memory");  // drain dummy stage

    // reduce across the 16 column-lanes of each row group
#pragma unroll
    for (int off = 1; off < 16; off <<= 1) {
        sp0 += __shfl_xor(sp0, off, 64);
        sp1 += __shfl_xor(sp1, off, 64);
        sp2 += __shfl_xor(sp2, off, 64);
        sp3 += __shfl_xor(sp3, off, 64);
    }
    if (nl == 0) {
        int m = kq * 4;
        float* o = scores + (size_t)b * SS + s0 + wave * 16 + m;
        o[0] = sp0; o[1] = sp1; o[2] = sp2; o[3] = sp3;
    }
#undef STAGE
}

// ---------------- K3: fused softmax + context partials ----------------
// block (b, scn): derive row max/sum from scores, weight 64-s chunk of enc.
__global__ void context_partial(const float* __restrict__ enc,
                                const float* __restrict__ sc,   // [B][S]
                                float* __restrict__ part) {     // [16][B][E]
    __shared__ float red[8];
    __shared__ float al[64];
    int bid = blockIdx.x;
    int b = bid >> 4, scn = bid & 15;
    int t = threadIdx.x, lane = t & 63, wave = t >> 6;

    f32x4 v = *(const f32x4*)(sc + (size_t)b * SS + t * 4);

    float m = fmaxf(fmaxf(v[0], v[1]), fmaxf(v[2], v[3]));
#pragma unroll
    for (int off = 1; off < 64; off <<= 1) m = fmaxf(m, __shfl_xor(m, off, 64));
    if (lane == 0) red[wave] = m;
    __syncthreads();
    m = fmaxf(fmaxf(red[0], red[1]), fmaxf(red[2], red[3]));

    float e0 = __expf(v[0] - m), e1 = __expf(v[1] - m);
    float e2 = __expf(v[2] - m), e3 = __expf(v[3] - m);
    float s = e0 + e1 + e2 + e3;
#pragma unroll
    for (int off = 1; off < 64; off <<= 1) s += __shfl_xor(s, off, 64);
    if (lane == 0) red[4 + wave] = s;
    __syncthreads();
    s = red[4] + red[5] + red[6] + red[7];
    float inv = 1.0f / s;

    // this block's 64-s chunk: rows scn*64 .. scn*64+63, held by threads
    // [scn*16, scn*16+16), 4 rows each
    if (t >= scn * 16 && t < scn * 16 + 16) {
        int i0 = (t - scn * 16) * 4;
        al[i0 + 0] = e0 * inv; al[i0 + 1] = e1 * inv;
        al[i0 + 2] = e2 * inv; al[i0 + 3] = e3 * inv;
    }
    __syncthreads();

    const float* basep = enc + ((size_t)b * SS + scn * 64) * EE;
    float a0 = 0.f, a1 = 0.f;
#pragma unroll 4
    for (int si = 0; si < 64; ++si) {
        float w = al[si];
        a0 = fmaf(w, basep[(size_t)si * EE + t], a0);
        a1 = fmaf(w, basep[(size_t)si * EE + t + 256], a1);
    }
    float* pp = part + ((size_t)scn * BB + b) * EE;
    pp[t] = a0;
    pp[t + 256] = a1;
}

// ---------------- K4: deterministic reduce of 16 partials ----------------
__global__ void context_reduce(const float* __restrict__ part,
                               float* __restrict__ out) {
    int g = blockIdx.x * 256 + threadIdx.x;  // 0..16383
    float s = 0.f;
#pragma unroll
    for (int scn = 0; scn < 16; ++scn) s += part[(size_t)scn * BB * EE + g];
    out[g] = s;
}

extern "C" void kernel_launch(void* const* d_in, const int* in_sizes, int n_in,
                              void* d_out, int out_size, void* d_ws, size_t ws_size,
                              hipStream_t stream) {
    const float* enc = (const float*)d_in[0];   // [B,S,E]
    const float* hid = (const float*)d_in[1];   // [B,D]
    const float* Wa  = (const float*)d_in[2];   // [D,U]
    const float* Ua  = (const float*)d_in[3];   // [E,U]
    const float* Va  = (const float*)d_in[4];   // [U]
    float* out = (float*)d_out;                 // [B,E]

    char* ws = (char*)d_ws;
    float*    decp   = (float*)(ws);                  //  64 KB
    float*    scores = (float*)(ws + 65536);          // 128 KB  [B][S]
    float*    part   = (float*)(ws + 196608);         //   1 MB  [16][B][E]
    ushort_t* UaSwz  = (ushort_t*)(ws + 1245184);     // 512 KB

    prep_kernel<<<384, 256, 0, stream>>>(Ua, hid, Wa, UaSwz, decp);
    scores_kernel<<<512, 256, 0, stream>>>(enc, UaSwz, decp, Va, scores);
    context_partial<<<512, 256, 0, stream>>>(enc, scores, part);
    context_reduce<<<64, 256, 0, stream>>>(part, out);
}